// Round 5
// baseline (4526.831 us; speedup 1.0000x reference)
//
#include <hip/hip_runtime.h>
#include <cstdint>
#include <cstddef>

// Decoder_55654186222328 — MI355X bf16-MFMA implementation (fixed d_in mapping:
// w_hh=d_in[22], b_ih=d_in[23] — previous rounds swapped these, deleting the
// LSTM h-recurrence).
// Shapes: B=128, A=64, M=512, H=128, HEADS=8, HD=16, T from input, OUT=2.
//   k1 convert_kernel: fp32 weights -> bf16 (wq pre-scaled by log2e/4), b4 = b_ih + b_hh.
//   k2 kv_kernel:      K[b][m][128] (bf16) and V^T[b][128][m] (bf16) — step-invariant.
//   k3 decoder_kernel: 256 blocks (2 per b, 32 agents) x 512 threads, loops T steps.
//       MFMA 16x16x32 bf16 everywhere; flash attention per wave=head with wave-private
//       LDS buffers; c in registers; h ping-pong bf16 in LDS + fp32 copy for state path;
//       softmax in exp2 domain (scale folded into wq).

typedef short short8 __attribute__((ext_vector_type(8)));
typedef float f32x4 __attribute__((ext_vector_type(4)));

#define LOG2E 1.4426950408889634f
#define QSCALE 0.36067376022224085f   /* log2(e)/4  (1/sqrt(HD)=1/4 folded in) */

__device__ __forceinline__ unsigned short f2bf(float f) {
  union { float f; unsigned int u; } v; v.f = f;
  unsigned int u = v.u;
  return (unsigned short)((u + 0x7fffu + ((u >> 16) & 1u)) >> 16);  // RNE
}
__device__ __forceinline__ float bf2f(unsigned short b) {
  union { unsigned int u; float f; } v; v.u = ((unsigned int)b) << 16;
  return v.f;
}
__device__ __forceinline__ float sigm(float x) {
  return 1.f / (1.f + exp2f(-LOG2E * x));
}
__device__ __forceinline__ float tanh_f(float x) {
  return 1.f - 2.f / (1.f + exp2f(2.f * LOG2E * x));
}
__device__ __forceinline__ f32x4 splat4(float v) { f32x4 r = {v, v, v, v}; return r; }

// ---------------------------------------------------------------- convert ----
__global__ __launch_bounds__(256) void convert_kernel(
    const float* __restrict__ wq, const float* __restrict__ wo,
    const float* __restrict__ w2, const float* __restrict__ w3,
    const float* __restrict__ wih, const float* __restrict__ whh,
    const float* __restrict__ bih, const float* __restrict__ bhh,
    const float* __restrict__ bq,
    unsigned short* __restrict__ WQ, unsigned short* __restrict__ WO,
    unsigned short* __restrict__ W2, unsigned short* __restrict__ W3,
    unsigned short* __restrict__ WIH, unsigned short* __restrict__ WHH,
    float* __restrict__ B4, float* __restrict__ BQS) {
  int i = blockIdx.x * 256 + threadIdx.x;
  if (i >= 180864) return;
  if (i < 16384)       WQ[i] = f2bf(wq[i] * QSCALE);
  else if (i < 32768)  WO[i - 16384] = f2bf(wo[i - 16384]);
  else if (i < 40960)  W2[i - 32768] = f2bf(w2[i - 32768]);
  else if (i < 49152)  W3[i - 40960] = f2bf(w3[i - 40960]);
  else if (i < 114688) WIH[i - 49152] = f2bf(wih[i - 49152]);
  else if (i < 180224) WHH[i - 114688] = f2bf(whh[i - 114688]);
  else if (i < 180736) { int j = i - 180224; B4[j] = bih[j] + bhh[j]; }
  else                 { int j = i - 180736; BQS[j] = bq[j] * QSCALE; }
}

// ---------------------------------------------------------------- K/V --------
// grid: 1024 = 128 b x 8 m-chunks of 64.  LDS: s_e[64][129] f32 + s_w[128][129] f32.
__global__ __launch_bounds__(256) void kv_kernel(
    const float* __restrict__ emb, const float* __restrict__ wk,
    const float* __restrict__ bk, const float* __restrict__ wv,
    const float* __restrict__ bv,
    unsigned short* __restrict__ Kbf, unsigned short* __restrict__ Vtbf) {
  extern __shared__ char smem[];
  float* s_e = (float*)smem;                 // [64][129]
  float* s_w = (float*)(smem + 33024);       // [128][129]
  const int tid = threadIdx.x;
  const int b = blockIdx.x >> 3;
  const int m0 = (blockIdx.x & 7) * 64;

  for (int i = tid; i < 8192; i += 256) {
    int row = i >> 7, col = i & 127;
    s_e[row * 129 + col] = emb[(size_t)(b * 512 + m0 + row) * 128 + col];
  }
  for (int i = tid; i < 16384; i += 256) {
    int row = i >> 7, col = i & 127;
    s_w[row * 129 + col] = wk[i];
  }
  __syncthreads();
  {  // K
    const int dg = tid & 31, rg = tid >> 5;
    float acc[8][4];
#pragma unroll
    for (int rr = 0; rr < 8; ++rr)
#pragma unroll
      for (int j = 0; j < 4; ++j) acc[rr][j] = 0.f;
    for (int k = 0; k < 128; ++k) {
      float e[8];
#pragma unroll
      for (int rr = 0; rr < 8; ++rr) e[rr] = s_e[(rg * 8 + rr) * 129 + k];
#pragma unroll
      for (int j = 0; j < 4; ++j) {
        float w = s_w[(dg * 4 + j) * 129 + k];
#pragma unroll
        for (int rr = 0; rr < 8; ++rr) acc[rr][j] = fmaf(e[rr], w, acc[rr][j]);
      }
    }
#pragma unroll
    for (int rr = 0; rr < 8; ++rr)
#pragma unroll
      for (int j = 0; j < 4; ++j) {
        int d = dg * 4 + j;
        Kbf[(size_t)(b * 512 + m0 + rg * 8 + rr) * 128 + d] = f2bf(acc[rr][j] + bk[d]);
      }
  }
  __syncthreads();
  for (int i = tid; i < 16384; i += 256) {
    int row = i >> 7, col = i & 127;
    s_w[row * 129 + col] = wv[i];
  }
  __syncthreads();
  {  // V transposed out
    const int r = tid & 63, dg = tid >> 6;
    float acc[32];
#pragma unroll
    for (int j = 0; j < 32; ++j) acc[j] = 0.f;
    for (int k = 0; k < 128; ++k) {
      float e = s_e[r * 129 + k];
#pragma unroll
      for (int j = 0; j < 32; ++j) acc[j] = fmaf(e, s_w[(dg * 32 + j) * 129 + k], acc[j]);
    }
#pragma unroll
    for (int j = 0; j < 32; ++j) {
      int d = dg * 32 + j;
      Vtbf[(size_t)(b * 128 + d) * 512 + m0 + r] = f2bf(acc[j] + bv[d]);
    }
  }
}

// ---------------------------------------------------------------- decoder ----
// grid 256 = 2 blocks per b (32 agents each); 512 threads = 8 waves.
// LDS carve (bytes):
//   s_h1   @0       [32][136] u16   8704
//   s_act  @8704    [32][136] u16   8704   (e1, later x)
//   s_q    @17408   [32][136] u16   8704
//   s_o    @26112   [32][136] u16   8704
//   s_h2   @34816   [32][72]  u16   4608
//   s_h    @39424   2x[32][136]u16 17408   (ping-pong, bf16)
//   s_state@56832   [32][2]   f32    256
//   s_mask @57088   [512]     f32   2048
//   s_K    @59136   8x[64][24]u16  24576   (per-wave)
//   s_V    @83712   8x[16][72]u16  18432   (per-wave)
//   s_P    @102144  8x[32][72]u16  36864   (per-wave)
//   s_hf   @139008  [32][128] f32  16384   (fp32 h for state path)
//   total 155392
__global__ __launch_bounds__(512) void decoder_kernel(
    const float* __restrict__ cf, const int* __restrict__ cav,
    const float* __restrict__ hid,
    const float* __restrict__ ctx, const int* __restrict__ mav,
    const int* __restrict__ ntp,
    const float* __restrict__ w1, const float* __restrict__ b1,
    const float* __restrict__ b2, const float* __restrict__ b3,
    const float* __restrict__ boP,
    const unsigned short* __restrict__ Kbf, const unsigned short* __restrict__ Vtbf,
    const unsigned short* __restrict__ WQ, const unsigned short* __restrict__ WO,
    const unsigned short* __restrict__ W2, const unsigned short* __restrict__ W3,
    const unsigned short* __restrict__ WIH, const unsigned short* __restrict__ WHH,
    const float* __restrict__ B4, const float* __restrict__ BQS,
    const float* __restrict__ lnw, const float* __restrict__ lnb,
    float* __restrict__ out) {
  extern __shared__ char smem[];
  unsigned short* s_h1 = (unsigned short*)(smem + 0);
  unsigned short* s_act = (unsigned short*)(smem + 8704);
  unsigned short* s_q = (unsigned short*)(smem + 17408);
  unsigned short* s_o = (unsigned short*)(smem + 26112);
  unsigned short* s_h2 = (unsigned short*)(smem + 34816);
  unsigned short* s_h = (unsigned short*)(smem + 39424);  // +buf*4352 (u16)
  float* s_state = (float*)(smem + 56832);
  float* s_mask = (float*)(smem + 57088);
  float* s_hf = (float*)(smem + 139008);  // [32][128] fp32

  const int tid = threadIdx.x;
  const int wave = tid >> 6;
  const int lane = tid & 63;
  const int quad = lane >> 4;
  const int l16 = lane & 15;
  unsigned short* s_K = (unsigned short*)(smem + 59136) + wave * 1536;   // [64][24]
  unsigned short* s_V = (unsigned short*)(smem + 83712) + wave * 1152;   // [16][72]
  unsigned short* s_P = (unsigned short*)(smem + 102144) + wave * 2304;  // [32][72]

  const int b = blockIdx.x >> 1;
  const int a0 = (blockIdx.x & 1) * 32;
  const int T = *ntp;
  const f32x4 zero4 = {0.f, 0.f, 0.f, 0.f};
  const short8 z8 = {0, 0, 0, 0, 0, 0, 0, 0};

  // ---- init ----
  if (tid < 64) {
    int a = tid >> 1, oi = tid & 1;
    s_state[a * 2 + oi] = cf[(size_t)(b * 64 + a0 + a) * 2 + oi];
  }
  if (tid < 512) {
    int m = tid;
    s_mask[m] = mav[b * 512 + m] ? 0.f : -1e30f;
  }
  {  // h0 -> bf16 buffer 0
    int idx = tid * 8;
    int a = idx >> 7, n0 = idx & 127;
    const float* hp = hid + (size_t)(b * 64 + a0 + a) * 128 + n0;
    short8 v;
#pragma unroll
    for (int j = 0; j < 8; ++j) v[j] = (short)f2bf(hp[j]);
    *(short8*)(s_h + a * 136 + n0) = v;
  }
  // c0 + avail registers: thread owns rows arow = mt*16+quad*4+r, col wave*16+l16
  float c_reg[2][4];
  float avl6[2][4];
#pragma unroll
  for (int mt = 0; mt < 2; ++mt)
#pragma unroll
    for (int r = 0; r < 4; ++r) {
      int a = mt * 16 + quad * 4 + r;
      c_reg[mt][r] = ctx[(size_t)(b * 64 + a0 + a) * 128 + wave * 16 + l16];
      avl6[mt][r] = (cav[b * 64 + a0 + a] != 0) ? 1.f : 0.f;
    }
  __syncthreads();

#pragma unroll 1
  for (int t = 0; t < T; ++t) {
    const int cur = t & 1, nxt = cur ^ 1;

    // ---- phase 0: h1 = relu(state @ w1^T + b1)  (VALU, K=2) ----
    {
      int a = tid >> 4;
      int n0 = (tid & 15) * 8;
      float st0 = s_state[a * 2], st1 = s_state[a * 2 + 1];
      const float* wp = w1 + n0 * 2;
      const float* bp = b1 + n0;
      short8 v;
#pragma unroll
      for (int j = 0; j < 8; ++j) {
        float x = fmaf(wp[j * 2], st0, fmaf(wp[j * 2 + 1], st1, bp[j]));
        v[j] = (short)f2bf(fmaxf(x, 0.f));
      }
      *(short8*)(s_h1 + a * 136 + n0) = v;
    }
    __syncthreads();

    // ---- phase 1: h2 = relu(h1 @ w2^T + b2)   M32 N64 K128 ----
    {
      int mt = wave >> 2, nt = wave & 3;
      f32x4 acc = splat4(b2[nt * 16 + l16]);
#pragma unroll
      for (int kt = 0; kt < 4; ++kt) {
        short8 a8 = *(const short8*)(s_h1 + (mt * 16 + l16) * 136 + kt * 32 + quad * 8);
        short8 b8 = *(const short8*)(W2 + ((nt * 16 + l16) * 128 + kt * 32 + quad * 8));
        acc = __builtin_amdgcn_mfma_f32_16x16x32_bf16(a8, b8, acc, 0, 0, 0);
      }
#pragma unroll
      for (int r = 0; r < 4; ++r)
        s_h2[(mt * 16 + quad * 4 + r) * 72 + nt * 16 + l16] = f2bf(fmaxf(acc[r], 0.f));
    }
    __syncthreads();

    // ---- phase 2: e1 = h2 @ w3^T + b3   M32 N128 K64 ----
    {
      int nt = wave;
      float bv = b3[nt * 16 + l16];
      short8 b8[2];
#pragma unroll
      for (int kt = 0; kt < 2; ++kt)
        b8[kt] = *(const short8*)(W3 + ((nt * 16 + l16) * 64 + kt * 32 + quad * 8));
#pragma unroll
      for (int mt = 0; mt < 2; ++mt) {
        f32x4 acc = splat4(bv);
#pragma unroll
        for (int kt = 0; kt < 2; ++kt) {
          short8 a8 = *(const short8*)(s_h2 + (mt * 16 + l16) * 72 + kt * 32 + quad * 8);
          acc = __builtin_amdgcn_mfma_f32_16x16x32_bf16(a8, b8[kt], acc, 0, 0, 0);
        }
#pragma unroll
        for (int r = 0; r < 4; ++r)
          s_act[(mt * 16 + quad * 4 + r) * 136 + nt * 16 + l16] = f2bf(acc[r]);
      }
    }
    __syncthreads();

    // ---- phase 3: q = e1 @ wq_s^T + bq_s   M32 N128 K128 (pre-scaled) ----
    {
      int nt = wave;
      float bv = BQS[nt * 16 + l16];
      short8 b8[4];
#pragma unroll
      for (int kt = 0; kt < 4; ++kt)
        b8[kt] = *(const short8*)(WQ + ((nt * 16 + l16) * 128 + kt * 32 + quad * 8));
#pragma unroll
      for (int mt = 0; mt < 2; ++mt) {
        f32x4 acc = splat4(bv);
#pragma unroll
        for (int kt = 0; kt < 4; ++kt) {
          short8 a8 = *(const short8*)(s_act + (mt * 16 + l16) * 136 + kt * 32 + quad * 8);
          acc = __builtin_amdgcn_mfma_f32_16x16x32_bf16(a8, b8[kt], acc, 0, 0, 0);
        }
#pragma unroll
        for (int r = 0; r < 4; ++r)
          s_q[(mt * 16 + quad * 4 + r) * 136 + nt * 16 + l16] = f2bf(acc[r]);
      }
    }
    __syncthreads();

    // ---- phase 4: flash attention, wave = head (wave-private buffers) ----
    {
      const int h = wave;
      short8 qA[2];
#pragma unroll
      for (int mt = 0; mt < 2; ++mt) {
        qA[mt] = z8;
        if (quad < 2)
          qA[mt] = *(const short8*)(s_q + (mt * 16 + l16) * 136 + h * 16 + quad * 8);
      }
      f32x4 O[2];
      O[0] = zero4;
      O[1] = zero4;
      float mr[2][4], lr[2][4];
#pragma unroll
      for (int mt = 0; mt < 2; ++mt)
#pragma unroll
        for (int r = 0; r < 4; ++r) {
          mr[mt][r] = -3.0e38f;
          lr[mt][r] = 0.f;
        }
      const int dr = lane >> 2, part = lane & 3;
      const size_t kbase = (size_t)(b * 512) * 128 + h * 16;
      const size_t vbase = (size_t)(b * 128 + h * 16 + dr) * 512 + part * 16;
      short8 k0n, k1n, v0n, v1n;
      {
        const short8* gp = (const short8*)(Kbf + kbase + (size_t)lane * 128);
        k0n = gp[0];
        k1n = gp[1];
        const short8* vp = (const short8*)(Vtbf + vbase);
        v0n = vp[0];
        v1n = vp[1];
      }
#pragma unroll 1
      for (int c = 0; c < 8; ++c) {
        const int m0 = c * 64;
        *(short8*)(s_K + lane * 24) = k0n;
        *(short8*)(s_K + lane * 24 + 8) = k1n;
        *(short8*)(s_V + dr * 72 + part * 16) = v0n;
        *(short8*)(s_V + dr * 72 + part * 16 + 8) = v1n;
        if (c < 7) {
          const short8* gp = (const short8*)(Kbf + kbase + (size_t)(m0 + 64 + lane) * 128);
          k0n = gp[0];
          k1n = gp[1];
          const short8* vp = (const short8*)(Vtbf + vbase + (m0 + 64));
          v0n = vp[0];
          v1n = vp[1];
        }
        f32x4 S[2][4];
#pragma unroll
        for (int nt = 0; nt < 4; ++nt) {
          short8 kB = z8;
          if (quad < 2)
            kB = *(const short8*)(s_K + (nt * 16 + l16) * 24 + quad * 8);
          S[0][nt] = __builtin_amdgcn_mfma_f32_16x16x32_bf16(qA[0], kB, zero4, 0, 0, 0);
          S[1][nt] = __builtin_amdgcn_mfma_f32_16x16x32_bf16(qA[1], kB, zero4, 0, 0, 0);
          float madd = s_mask[m0 + nt * 16 + l16];
#pragma unroll
          for (int r = 0; r < 4; ++r) {
            S[0][nt][r] += madd;
            S[1][nt][r] += madd;
          }
        }
#pragma unroll
        for (int mt = 0; mt < 2; ++mt) {
#pragma unroll
          for (int r = 0; r < 4; ++r) {
            float s0v = S[mt][0][r], s1v = S[mt][1][r], s2v = S[mt][2][r], s3v = S[mt][3][r];
            float sm = fmaxf(fmaxf(s0v, s1v), fmaxf(s2v, s3v));
            sm = fmaxf(sm, __shfl_xor(sm, 1));
            sm = fmaxf(sm, __shfl_xor(sm, 2));
            sm = fmaxf(sm, __shfl_xor(sm, 4));
            sm = fmaxf(sm, __shfl_xor(sm, 8));
            float mnew = fmaxf(mr[mt][r], sm);
            float alpha = exp2f(mr[mt][r] - mnew);
            float p0 = exp2f(s0v - mnew), p1 = exp2f(s1v - mnew);
            float p2 = exp2f(s2v - mnew), p3 = exp2f(s3v - mnew);
            float rs = (p0 + p1) + (p2 + p3);
            rs += __shfl_xor(rs, 1);
            rs += __shfl_xor(rs, 2);
            rs += __shfl_xor(rs, 4);
            rs += __shfl_xor(rs, 8);
            lr[mt][r] = lr[mt][r] * alpha + rs;
            mr[mt][r] = mnew;
            O[mt][r] *= alpha;
            int rowb = (mt * 16 + quad * 4 + r) * 72;
            s_P[rowb + l16] = f2bf(p0);
            s_P[rowb + 16 + l16] = f2bf(p1);
            s_P[rowb + 32 + l16] = f2bf(p2);
            s_P[rowb + 48 + l16] = f2bf(p3);
          }
        }
#pragma unroll
        for (int mt = 0; mt < 2; ++mt) {
#pragma unroll
          for (int kt = 0; kt < 2; ++kt) {
            short8 a8 = *(const short8*)(s_P + (mt * 16 + l16) * 72 + kt * 32 + quad * 8);
            short8 b8 = *(const short8*)(s_V + l16 * 72 + kt * 32 + quad * 8);
            O[mt] = __builtin_amdgcn_mfma_f32_16x16x32_bf16(a8, b8, O[mt], 0, 0, 0);
          }
        }
      }
#pragma unroll
      for (int mt = 0; mt < 2; ++mt)
#pragma unroll
        for (int r = 0; r < 4; ++r) {
          float inv = 1.f / lr[mt][r];
          s_o[(mt * 16 + quad * 4 + r) * 136 + h * 16 + l16] = f2bf(O[mt][r] * inv);
        }
    }
    __syncthreads();

    // ---- phase 5: x = o @ wo^T + bo   M32 N128 K128 ----
    {
      int nt = wave;
      float bv = boP[nt * 16 + l16];
      short8 b8[4];
#pragma unroll
      for (int kt = 0; kt < 4; ++kt)
        b8[kt] = *(const short8*)(WO + ((nt * 16 + l16) * 128 + kt * 32 + quad * 8));
#pragma unroll
      for (int mt = 0; mt < 2; ++mt) {
        f32x4 acc = splat4(bv);
#pragma unroll
        for (int kt = 0; kt < 4; ++kt) {
          short8 a8 = *(const short8*)(s_o + (mt * 16 + l16) * 136 + kt * 32 + quad * 8);
          acc = __builtin_amdgcn_mfma_f32_16x16x32_bf16(a8, b8[kt], acc, 0, 0, 0);
        }
#pragma unroll
        for (int r = 0; r < 4; ++r)
          s_act[(mt * 16 + quad * 4 + r) * 136 + nt * 16 + l16] = f2bf(acc[r]);
      }
    }
    __syncthreads();

    // ---- phase 6: LSTM gates + elementwise ----
    {
      const int ni = wave;
      const int wrow = ni * 16 + l16;
      const float bi = B4[wrow], bfv = B4[128 + wrow], bg = B4[256 + wrow], bov = B4[384 + wrow];
      f32x4 gi[2], gf[2], gg[2], go[2];
#pragma unroll
      for (int mt = 0; mt < 2; ++mt) {
        gi[mt] = splat4(bi);
        gf[mt] = splat4(bfv);
        gg[mt] = splat4(bg);
        go[mt] = splat4(bov);
      }
      const unsigned short* hbuf = s_h + cur * 4352;
#pragma unroll
      for (int kt = 0; kt < 4; ++kt) {
        short8 b_i = *(const short8*)(WIH + ((0 + wrow) * 128 + kt * 32 + quad * 8));
        short8 b_f = *(const short8*)(WIH + ((128 + wrow) * 128 + kt * 32 + quad * 8));
        short8 b_g = *(const short8*)(WIH + ((256 + wrow) * 128 + kt * 32 + quad * 8));
        short8 b_o = *(const short8*)(WIH + ((384 + wrow) * 128 + kt * 32 + quad * 8));
#pragma unroll
        for (int mt = 0; mt < 2; ++mt) {
          short8 a8 = *(const short8*)(s_act + (mt * 16 + l16) * 136 + kt * 32 + quad * 8);
          gi[mt] = __builtin_amdgcn_mfma_f32_16x16x32_bf16(a8, b_i, gi[mt], 0, 0, 0);
          gf[mt] = __builtin_amdgcn_mfma_f32_16x16x32_bf16(a8, b_f, gf[mt], 0, 0, 0);
          gg[mt] = __builtin_amdgcn_mfma_f32_16x16x32_bf16(a8, b_g, gg[mt], 0, 0, 0);
          go[mt] = __builtin_amdgcn_mfma_f32_16x16x32_bf16(a8, b_o, go[mt], 0, 0, 0);
        }
      }
#pragma unroll
      for (int kt = 0; kt < 4; ++kt) {
        short8 b_i = *(const short8*)(WHH + ((0 + wrow) * 128 + kt * 32 + quad * 8));
        short8 b_f = *(const short8*)(WHH + ((128 + wrow) * 128 + kt * 32 + quad * 8));
        short8 b_g = *(const short8*)(WHH + ((256 + wrow) * 128 + kt * 32 + quad * 8));
        short8 b_o = *(const short8*)(WHH + ((384 + wrow) * 128 + kt * 32 + quad * 8));
#pragma unroll
        for (int mt = 0; mt < 2; ++mt) {
          short8 a8 = *(const short8*)(hbuf + (mt * 16 + l16) * 136 + kt * 32 + quad * 8);
          gi[mt] = __builtin_amdgcn_mfma_f32_16x16x32_bf16(a8, b_i, gi[mt], 0, 0, 0);
          gf[mt] = __builtin_amdgcn_mfma_f32_16x16x32_bf16(a8, b_f, gf[mt], 0, 0, 0);
          gg[mt] = __builtin_amdgcn_mfma_f32_16x16x32_bf16(a8, b_g, gg[mt], 0, 0, 0);
          go[mt] = __builtin_amdgcn_mfma_f32_16x16x32_bf16(a8, b_o, go[mt], 0, 0, 0);
        }
      }
      unsigned short* hn = s_h + nxt * 4352;
#pragma unroll
      for (int mt = 0; mt < 2; ++mt) {
#pragma unroll
        for (int r = 0; r < 4; ++r) {
          float iv = sigm(gi[mt][r]);
          float fv = sigm(gf[mt][r]);
          float gv = tanh_f(gg[mt][r]);
          float ov = sigm(go[mt][r]);
          float cn = fmaf(fv, c_reg[mt][r], iv * gv);
          float hv = ov * tanh_f(cn);
          int arow = mt * 16 + quad * 4 + r;
          float av = avl6[mt][r];
          float hold = bf2f(hbuf[arow * 136 + ni * 16 + l16]);
          cn = av * cn + (1.f - av) * c_reg[mt][r];
          hv = av * hv + (1.f - av) * hold;
          c_reg[mt][r] = cn;
          hn[arow * 136 + ni * 16 + l16] = f2bf(hv);
          s_hf[arow * 128 + ni * 16 + l16] = hv;  // fp32 copy for state path
        }
      }
    }
    __syncthreads();

    // ---- phase 7: state += h @ lin_w^T + lin_b; emit output (fp32 h) ----
    if (tid < 64) {
      int a = tid >> 1, oi = tid & 1;
      const float* lw = lnw + oi * 128;
      const float* hp = s_hf + a * 128;
      float accd = 0.f;
#pragma unroll
      for (int k = 0; k < 128; ++k) accd = fmaf(hp[k], lw[k], accd);
      float ns = s_state[a * 2 + oi] + accd + lnb[oi];
      s_state[a * 2 + oi] = ns;
      out[((size_t)(b * 64 + a0 + a) * T + t) * 2 + oi] = ns;
    }
    __syncthreads();
  }
}

// ---------------------------------------------------------------- launch ----
extern "C" void kernel_launch(void* const* d_in, const int* in_sizes, int n_in,
                              void* d_out, int out_size, void* d_ws, size_t ws_size,
                              hipStream_t stream) {
  (void)in_sizes; (void)n_in; (void)out_size; (void)ws_size;
  const float* cf = (const float*)d_in[0];
  const int* cav = (const int*)d_in[1];
  const float* hid = (const float*)d_in[2];
  const float* ctx = (const float*)d_in[3];
  const float* emb = (const float*)d_in[4];
  const int* mav = (const int*)d_in[5];   // bool -> int32
  const int* ntp = (const int*)d_in[6];
  const float* w1 = (const float*)d_in[7];
  const float* b1 = (const float*)d_in[8];
  const float* w2 = (const float*)d_in[9];
  const float* b2 = (const float*)d_in[10];
  const float* w3 = (const float*)d_in[11];
  const float* b3 = (const float*)d_in[12];
  const float* wq = (const float*)d_in[13];
  const float* bq = (const float*)d_in[14];
  const float* wk = (const float*)d_in[15];
  const float* bk = (const float*)d_in[16];
  const float* wv = (const float*)d_in[17];
  const float* bv = (const float*)d_in[18];
  const float* wo = (const float*)d_in[19];
  const float* bo = (const float*)d_in[20];
  const float* wih = (const float*)d_in[21];  // w_ih
  const float* whh = (const float*)d_in[22];  // w_hh   (FIXED)
  const float* bih = (const float*)d_in[23];  // b_ih   (FIXED)
  const float* bhh = (const float*)d_in[24];  // b_hh
  const float* lnw = (const float*)d_in[25];
  const float* lnb = (const float*)d_in[26];

  char* ws = (char*)d_ws;
  unsigned short* Kbf = (unsigned short*)(ws + 0);
  unsigned short* Vtbf = (unsigned short*)(ws + 16777216);
  unsigned short* WQs = (unsigned short*)(ws + 33554432);
  unsigned short* WOs = (unsigned short*)(ws + 33587200);
  unsigned short* W2s = (unsigned short*)(ws + 33619968);
  unsigned short* W3s = (unsigned short*)(ws + 33636352);
  unsigned short* WIHs = (unsigned short*)(ws + 33652736);
  unsigned short* WHHs = (unsigned short*)(ws + 33783808);
  float* B4s = (float*)(ws + 33914880);
  float* BQSs = (float*)(ws + 33916928);

  (void)hipFuncSetAttribute((const void*)kv_kernel,
                            hipFuncAttributeMaxDynamicSharedMemorySize, 99072);
  (void)hipFuncSetAttribute((const void*)decoder_kernel,
                            hipFuncAttributeMaxDynamicSharedMemorySize, 155392);

  convert_kernel<<<707, 256, 0, stream>>>(wq, wo, w2, w3, wih, whh, bih, bhh, bq,
                                          WQs, WOs, W2s, W3s, WIHs, WHHs, B4s, BQSs);
  kv_kernel<<<1024, 256, 99072, stream>>>(emb, wk, bk, wv, bv, Kbf, Vtbf);
  decoder_kernel<<<256, 512, 155392, stream>>>(
      cf, cav, hid, ctx, mav, ntp, w1, b1, b2, b3, bo, Kbf, Vtbf, WQs, WOs, W2s, W3s,
      WIHs, WHHs, B4s, BQSs, lnw, lnb, (float*)d_out);
}

// Round 7
// 4283.705 us; speedup vs baseline: 1.0568x; 1.0568x over previous
//
#include <hip/hip_runtime.h>
#include <cstdint>
#include <cstddef>

// Decoder_55654186222328 — MI355X bf16-MFMA, R7 (= R6 with short4 name fix).
// vs R5: (1) no-max exp2 softmax + MFMA-ones denominator (removes 512 serial
// cross-lane ops/wave/step), (2) 512 blocks x 16 agents, LDS 76160 B -> 2
// blocks/CU, (3) same-XCD block swizzle for K/V L2 residency.

typedef short bf16x4v __attribute__((ext_vector_type(4)));
typedef short short8 __attribute__((ext_vector_type(8)));
typedef float f32x4 __attribute__((ext_vector_type(4)));

#define LOG2E 1.4426950408889634f
#define QSCALE 0.36067376022224085f   /* log2(e)/4 */

__device__ __forceinline__ unsigned short f2bf(float f) {
  union { float f; unsigned int u; } v; v.f = f;
  unsigned int u = v.u;
  return (unsigned short)((u + 0x7fffu + ((u >> 16) & 1u)) >> 16);  // RNE
}
__device__ __forceinline__ float bf2f(unsigned short b) {
  union { unsigned int u; float f; } v; v.u = ((unsigned int)b) << 16;
  return v.f;
}
__device__ __forceinline__ float sigm(float x) {
  return 1.f / (1.f + exp2f(-LOG2E * x));
}
__device__ __forceinline__ float tanh_f(float x) {
  return 1.f - 2.f / (1.f + exp2f(2.f * LOG2E * x));
}
__device__ __forceinline__ f32x4 splat4(float v) { f32x4 r = {v, v, v, v}; return r; }

// ---------------------------------------------------------------- convert ----
__global__ __launch_bounds__(256) void convert_kernel(
    const float* __restrict__ wq, const float* __restrict__ wo,
    const float* __restrict__ w2, const float* __restrict__ w3,
    const float* __restrict__ wih, const float* __restrict__ whh,
    const float* __restrict__ bih, const float* __restrict__ bhh,
    const float* __restrict__ bq,
    unsigned short* __restrict__ WQ, unsigned short* __restrict__ WO,
    unsigned short* __restrict__ W2, unsigned short* __restrict__ W3,
    unsigned short* __restrict__ WIH, unsigned short* __restrict__ WHH,
    float* __restrict__ B4, float* __restrict__ BQS) {
  int i = blockIdx.x * 256 + threadIdx.x;
  if (i >= 180864) return;
  if (i < 16384)       WQ[i] = f2bf(wq[i] * QSCALE);
  else if (i < 32768)  WO[i - 16384] = f2bf(wo[i - 16384]);
  else if (i < 40960)  W2[i - 32768] = f2bf(w2[i - 32768]);
  else if (i < 49152)  W3[i - 40960] = f2bf(w3[i - 40960]);
  else if (i < 114688) WIH[i - 49152] = f2bf(wih[i - 49152]);
  else if (i < 180224) WHH[i - 114688] = f2bf(whh[i - 114688]);
  else if (i < 180736) { int j = i - 180224; B4[j] = bih[j] + bhh[j]; }
  else                 { int j = i - 180736; BQS[j] = bq[j] * QSCALE; }
}

// ---------------------------------------------------------------- K/V --------
__global__ __launch_bounds__(256) void kv_kernel(
    const float* __restrict__ emb, const float* __restrict__ wk,
    const float* __restrict__ bk, const float* __restrict__ wv,
    const float* __restrict__ bv,
    unsigned short* __restrict__ Kbf, unsigned short* __restrict__ Vtbf) {
  extern __shared__ char smem[];
  float* s_e = (float*)smem;                 // [64][129]
  float* s_w = (float*)(smem + 33024);       // [128][129]
  const int tid = threadIdx.x;
  const int b = blockIdx.x >> 3;
  const int m0 = (blockIdx.x & 7) * 64;

  for (int i = tid; i < 8192; i += 256) {
    int row = i >> 7, col = i & 127;
    s_e[row * 129 + col] = emb[(size_t)(b * 512 + m0 + row) * 128 + col];
  }
  for (int i = tid; i < 16384; i += 256) {
    int row = i >> 7, col = i & 127;
    s_w[row * 129 + col] = wk[i];
  }
  __syncthreads();
  {  // K
    const int dg = tid & 31, rg = tid >> 5;
    float acc[8][4];
#pragma unroll
    for (int rr = 0; rr < 8; ++rr)
#pragma unroll
      for (int j = 0; j < 4; ++j) acc[rr][j] = 0.f;
    for (int k = 0; k < 128; ++k) {
      float e[8];
#pragma unroll
      for (int rr = 0; rr < 8; ++rr) e[rr] = s_e[(rg * 8 + rr) * 129 + k];
#pragma unroll
      for (int j = 0; j < 4; ++j) {
        float w = s_w[(dg * 4 + j) * 129 + k];
#pragma unroll
        for (int rr = 0; rr < 8; ++rr) acc[rr][j] = fmaf(e[rr], w, acc[rr][j]);
      }
    }
#pragma unroll
    for (int rr = 0; rr < 8; ++rr)
#pragma unroll
      for (int j = 0; j < 4; ++j) {
        int d = dg * 4 + j;
        Kbf[(size_t)(b * 512 + m0 + rg * 8 + rr) * 128 + d] = f2bf(acc[rr][j] + bk[d]);
      }
  }
  __syncthreads();
  for (int i = tid; i < 16384; i += 256) {
    int row = i >> 7, col = i & 127;
    s_w[row * 129 + col] = wv[i];
  }
  __syncthreads();
  {  // V transposed out
    const int r = tid & 63, dg = tid >> 6;
    float acc[32];
#pragma unroll
    for (int j = 0; j < 32; ++j) acc[j] = 0.f;
    for (int k = 0; k < 128; ++k) {
      float e = s_e[r * 129 + k];
#pragma unroll
      for (int j = 0; j < 32; ++j) acc[j] = fmaf(e, s_w[(dg * 32 + j) * 129 + k], acc[j]);
    }
#pragma unroll
    for (int j = 0; j < 32; ++j) {
      int d = dg * 32 + j;
      Vtbf[(size_t)(b * 128 + d) * 512 + m0 + r] = f2bf(acc[j] + bv[d]);
    }
  }
}

// ---------------------------------------------------------------- decoder ----
// grid 512: b = blockIdx&127, a0 = (blockIdx>>7)*16 — same-b blocks 128 apart
// (same XCD under mod-8 placement) for K/V L2 residency. 512 thr = 8 waves.
// LDS (76160 B total, 2 blocks/CU):
//   s_buf1 @0      [16][136]u16  4352  (h1 / q / x)
//   s_buf2 @4352   [16][136]u16  4352  (e / o)
//   s_h2   @8704   [16][72] u16  2304
//   s_h    @11008  2x[16][136]   8704  (ping-pong bf16)
//   s_state@19712  [16][2] f32    128
//   s_mask @19840  [512]  f32    2048
//   s_K    @21888  [64][136]u16 17408  (shared; wave h owns cols h*16..+15)
//   s_V    @39296  [128][72]u16 18432  (shared; wave h owns rows h*16..+15)
//   s_P    @57728  8x[16][72]   18432  (per-wave)
__global__ __launch_bounds__(512, 4) void decoder_kernel(
    const float* __restrict__ cf, const int* __restrict__ cav,
    const float* __restrict__ hid,
    const float* __restrict__ ctx, const int* __restrict__ mav,
    const int* __restrict__ ntp,
    const float* __restrict__ w1, const float* __restrict__ b1,
    const float* __restrict__ b2, const float* __restrict__ b3,
    const float* __restrict__ boP,
    const unsigned short* __restrict__ Kbf, const unsigned short* __restrict__ Vtbf,
    const unsigned short* __restrict__ WQ, const unsigned short* __restrict__ WO,
    const unsigned short* __restrict__ W2, const unsigned short* __restrict__ W3,
    const unsigned short* __restrict__ WIH, const unsigned short* __restrict__ WHH,
    const float* __restrict__ B4, const float* __restrict__ BQS,
    const float* __restrict__ lnw, const float* __restrict__ lnb,
    float* __restrict__ out) {
  extern __shared__ char smem[];
  unsigned short* s_buf1 = (unsigned short*)(smem + 0);
  unsigned short* s_buf2 = (unsigned short*)(smem + 4352);
  unsigned short* s_h2 = (unsigned short*)(smem + 8704);
  unsigned short* s_h = (unsigned short*)(smem + 11008);  // +buf*2176 (u16)
  float* s_state = (float*)(smem + 19712);
  float* s_mask = (float*)(smem + 19840);
  unsigned short* s_K = (unsigned short*)(smem + 21888);  // [64][136]
  unsigned short* s_V = (unsigned short*)(smem + 39296);  // [128][72]
  unsigned short* s_P = (unsigned short*)(smem + 57728);  // + wave*1152 u16

  const int tid = threadIdx.x;
  const int wave = tid >> 6;
  const int lane = tid & 63;
  const int quad = lane >> 4;
  const int l16 = lane & 15;
  unsigned short* s_Pw = s_P + wave * 1152;  // [16][72]

  const int b = blockIdx.x & 127;
  const int a0 = (blockIdx.x >> 7) * 16;
  const int T = *ntp;
  const f32x4 zero4 = {0.f, 0.f, 0.f, 0.f};
  const short8 z8 = {0, 0, 0, 0, 0, 0, 0, 0};
  const short8 ones8 = {0x3F80, 0x3F80, 0x3F80, 0x3F80,
                        0x3F80, 0x3F80, 0x3F80, 0x3F80};  // bf16 1.0 x8

  // ---- init ----
  if (tid < 32) {
    int a = tid >> 1, oi = tid & 1;
    s_state[a * 2 + oi] = cf[(size_t)(b * 64 + a0 + a) * 2 + oi];
  }
  s_mask[tid] = mav[b * 512 + tid] ? 0.f : -1e30f;
  {  // h0 -> bf16 buffer 0 (16 agents x 128 = 2048; 4/thread)
    int idx = tid * 4;
    int a = idx >> 7, n0 = idx & 127;
    const float* hp = hid + (size_t)(b * 64 + a0 + a) * 128 + n0;
    bf16x4v v;
#pragma unroll
    for (int j = 0; j < 4; ++j) v[j] = (short)f2bf(hp[j]);
    *(bf16x4v*)(s_h + a * 136 + n0) = v;
  }
  // c0 + avail: thread owns rows quad*4+r, col wave*16+l16 (P6 layout)
  float c_reg[4], avl[4];
#pragma unroll
  for (int r = 0; r < 4; ++r) {
    int a = quad * 4 + r;
    c_reg[r] = ctx[(size_t)(b * 64 + a0 + a) * 128 + wave * 16 + l16];
    avl[r] = (cav[b * 64 + a0 + a] != 0) ? 1.f : 0.f;
  }
  __syncthreads();

#pragma unroll 1
  for (int t = 0; t < T; ++t) {
    const int cur = t & 1, nxt = cur ^ 1;

    // ---- P0: h1 = relu(state @ w1^T + b1)  (VALU, K=2) ----
    {
      int a = tid >> 5;
      int n0 = (tid & 31) * 4;
      float st0 = s_state[a * 2], st1 = s_state[a * 2 + 1];
      const float* wp = w1 + n0 * 2;
      const float* bp = b1 + n0;
      bf16x4v v;
#pragma unroll
      for (int j = 0; j < 4; ++j) {
        float x = fmaf(wp[j * 2], st0, fmaf(wp[j * 2 + 1], st1, bp[j]));
        v[j] = (short)f2bf(fmaxf(x, 0.f));
      }
      *(bf16x4v*)(s_buf1 + a * 136 + n0) = v;
    }
    __syncthreads();

    // ---- P1: h2 = relu(h1 @ w2^T + b2)   M16 N64 K128 (waves 0..3) ----
    if (wave < 4) {
      int nt = wave;
      f32x4 acc = splat4(b2[nt * 16 + l16]);
#pragma unroll
      for (int kt = 0; kt < 4; ++kt) {
        short8 a8 = *(const short8*)(s_buf1 + l16 * 136 + kt * 32 + quad * 8);
        short8 b8 = *(const short8*)(W2 + ((nt * 16 + l16) * 128 + kt * 32 + quad * 8));
        acc = __builtin_amdgcn_mfma_f32_16x16x32_bf16(a8, b8, acc, 0, 0, 0);
      }
#pragma unroll
      for (int r = 0; r < 4; ++r)
        s_h2[(quad * 4 + r) * 72 + nt * 16 + l16] = f2bf(fmaxf(acc[r], 0.f));
    }
    __syncthreads();

    // ---- P2: e = h2 @ w3^T + b3   M16 N128 K64 -> s_buf2 ----
    {
      int nt = wave;
      f32x4 acc = splat4(b3[nt * 16 + l16]);
#pragma unroll
      for (int kt = 0; kt < 2; ++kt) {
        short8 a8 = *(const short8*)(s_h2 + l16 * 72 + kt * 32 + quad * 8);
        short8 b8 = *(const short8*)(W3 + ((nt * 16 + l16) * 64 + kt * 32 + quad * 8));
        acc = __builtin_amdgcn_mfma_f32_16x16x32_bf16(a8, b8, acc, 0, 0, 0);
      }
#pragma unroll
      for (int r = 0; r < 4; ++r)
        s_buf2[(quad * 4 + r) * 136 + nt * 16 + l16] = f2bf(acc[r]);
    }
    __syncthreads();

    // ---- P3: q = e @ wq_s^T + bq_s   M16 N128 K128 -> s_buf1 ----
    {
      int nt = wave;
      f32x4 acc = splat4(BQS[nt * 16 + l16]);
#pragma unroll
      for (int kt = 0; kt < 4; ++kt) {
        short8 a8 = *(const short8*)(s_buf2 + l16 * 136 + kt * 32 + quad * 8);
        short8 b8 = *(const short8*)(WQ + ((nt * 16 + l16) * 128 + kt * 32 + quad * 8));
        acc = __builtin_amdgcn_mfma_f32_16x16x32_bf16(a8, b8, acc, 0, 0, 0);
      }
#pragma unroll
      for (int r = 0; r < 4; ++r)
        s_buf1[(quad * 4 + r) * 136 + nt * 16 + l16] = f2bf(acc[r]);
    }
    __syncthreads();

    // ---- P4: attention, wave = head. exp2-domain, no max; L via ones-MFMA ----
    {
      const int h = wave;
      short8 qA = z8;
      if (quad < 2)
        qA = *(const short8*)(s_buf1 + l16 * 136 + h * 16 + quad * 8);
      f32x4 O = zero4, L = zero4;
      const int dr = lane >> 2, part = lane & 3;
      const size_t kbase = (size_t)(b * 512) * 128 + h * 16;
      const size_t vbase = (size_t)(b * 128 + h * 16 + dr) * 512 + part * 16;
      short8 k0n, k1n, v0n, v1n;
      {
        const short8* gp = (const short8*)(Kbf + kbase + (size_t)lane * 128);
        k0n = gp[0];
        k1n = gp[1];
        const short8* vp = (const short8*)(Vtbf + vbase);
        v0n = vp[0];
        v1n = vp[1];
      }
#pragma unroll 1
      for (int c = 0; c < 8; ++c) {
        const int m0c = c * 64;
        // commit staged regs (wave-private slices of shared buffers)
        *(short8*)(s_K + lane * 136 + h * 16) = k0n;
        *(short8*)(s_K + lane * 136 + h * 16 + 8) = k1n;
        *(short8*)(s_V + (h * 16 + dr) * 72 + part * 16) = v0n;
        *(short8*)(s_V + (h * 16 + dr) * 72 + part * 16 + 8) = v1n;
        if (c < 7) {
          const short8* gp = (const short8*)(Kbf + kbase + (size_t)(m0c + 64 + lane) * 128);
          k0n = gp[0];
          k1n = gp[1];
          const short8* vp = (const short8*)(Vtbf + vbase + (m0c + 64));
          v0n = vp[0];
          v1n = vp[1];
        }
        // scores (exp2 domain; scale folded into wq) + mask
        f32x4 S[4];
#pragma unroll
        for (int nt = 0; nt < 4; ++nt) {
          short8 kB = z8;
          if (quad < 2)
            kB = *(const short8*)(s_K + (nt * 16 + l16) * 136 + h * 16 + quad * 8);
          S[nt] = __builtin_amdgcn_mfma_f32_16x16x32_bf16(qA, kB, zero4, 0, 0, 0);
          float madd = s_mask[m0c + nt * 16 + l16];
#pragma unroll
          for (int r = 0; r < 4; ++r) S[nt][r] += madd;
        }
        // p = exp2(s) (masked -> 0), store bf16 P
#pragma unroll
        for (int nt = 0; nt < 4; ++nt)
#pragma unroll
          for (int r = 0; r < 4; ++r)
            s_Pw[(quad * 4 + r) * 72 + nt * 16 + l16] = f2bf(exp2f(S[nt][r]));
        // O += P V ; L += P 1  (same bf16 P -> rounding cancels in O/L)
#pragma unroll
        for (int kt = 0; kt < 2; ++kt) {
          short8 a8 = *(const short8*)(s_Pw + l16 * 72 + kt * 32 + quad * 8);
          short8 b8 = *(const short8*)(s_V + (h * 16 + l16) * 72 + kt * 32 + quad * 8);
          O = __builtin_amdgcn_mfma_f32_16x16x32_bf16(a8, b8, O, 0, 0, 0);
          L = __builtin_amdgcn_mfma_f32_16x16x32_bf16(a8, ones8, L, 0, 0, 0);
        }
      }
#pragma unroll
      for (int r = 0; r < 4; ++r) {
        float inv = 1.f / L[r];
        s_buf2[(quad * 4 + r) * 136 + h * 16 + l16] = f2bf(O[r] * inv);
      }
    }
    __syncthreads();

    // ---- P5: x = o @ wo^T + bo   M16 N128 K128 -> s_buf1 ----
    {
      int nt = wave;
      f32x4 acc = splat4(boP[nt * 16 + l16]);
#pragma unroll
      for (int kt = 0; kt < 4; ++kt) {
        short8 a8 = *(const short8*)(s_buf2 + l16 * 136 + kt * 32 + quad * 8);
        short8 b8 = *(const short8*)(WO + ((nt * 16 + l16) * 128 + kt * 32 + quad * 8));
        acc = __builtin_amdgcn_mfma_f32_16x16x32_bf16(a8, b8, acc, 0, 0, 0);
      }
#pragma unroll
      for (int r = 0; r < 4; ++r)
        s_buf1[(quad * 4 + r) * 136 + nt * 16 + l16] = f2bf(acc[r]);
    }
    __syncthreads();

    // ---- P6: LSTM gates + elementwise ----
    {
      const int ni = wave;
      const int wrow = ni * 16 + l16;
      f32x4 gi = splat4(B4[wrow]);
      f32x4 gf = splat4(B4[128 + wrow]);
      f32x4 gg = splat4(B4[256 + wrow]);
      f32x4 go = splat4(B4[384 + wrow]);
      const unsigned short* hbuf = s_h + cur * 2176;
#pragma unroll
      for (int kt = 0; kt < 4; ++kt) {
        short8 a8 = *(const short8*)(s_buf1 + l16 * 136 + kt * 32 + quad * 8);
        short8 b_i = *(const short8*)(WIH + ((0 + wrow) * 128 + kt * 32 + quad * 8));
        short8 b_f = *(const short8*)(WIH + ((128 + wrow) * 128 + kt * 32 + quad * 8));
        short8 b_g = *(const short8*)(WIH + ((256 + wrow) * 128 + kt * 32 + quad * 8));
        short8 b_o = *(const short8*)(WIH + ((384 + wrow) * 128 + kt * 32 + quad * 8));
        gi = __builtin_amdgcn_mfma_f32_16x16x32_bf16(a8, b_i, gi, 0, 0, 0);
        gf = __builtin_amdgcn_mfma_f32_16x16x32_bf16(a8, b_f, gf, 0, 0, 0);
        gg = __builtin_amdgcn_mfma_f32_16x16x32_bf16(a8, b_g, gg, 0, 0, 0);
        go = __builtin_amdgcn_mfma_f32_16x16x32_bf16(a8, b_o, go, 0, 0, 0);
      }
#pragma unroll
      for (int kt = 0; kt < 4; ++kt) {
        short8 a8 = *(const short8*)(hbuf + l16 * 136 + kt * 32 + quad * 8);
        short8 b_i = *(const short8*)(WHH + ((0 + wrow) * 128 + kt * 32 + quad * 8));
        short8 b_f = *(const short8*)(WHH + ((128 + wrow) * 128 + kt * 32 + quad * 8));
        short8 b_g = *(const short8*)(WHH + ((256 + wrow) * 128 + kt * 32 + quad * 8));
        short8 b_o = *(const short8*)(WHH + ((384 + wrow) * 128 + kt * 32 + quad * 8));
        gi = __builtin_amdgcn_mfma_f32_16x16x32_bf16(a8, b_i, gi, 0, 0, 0);
        gf = __builtin_amdgcn_mfma_f32_16x16x32_bf16(a8, b_f, gf, 0, 0, 0);
        gg = __builtin_amdgcn_mfma_f32_16x16x32_bf16(a8, b_g, gg, 0, 0, 0);
        go = __builtin_amdgcn_mfma_f32_16x16x32_bf16(a8, b_o, go, 0, 0, 0);
      }
      unsigned short* hn = s_h + nxt * 2176;
#pragma unroll
      for (int r = 0; r < 4; ++r) {
        float iv = sigm(gi[r]);
        float fv = sigm(gf[r]);
        float gv = tanh_f(gg[r]);
        float ov = sigm(go[r]);
        float cn = fmaf(fv, c_reg[r], iv * gv);
        float hv = ov * tanh_f(cn);
        int arow = quad * 4 + r;
        float av = avl[r];
        float hold = bf2f(hbuf[arow * 136 + ni * 16 + l16]);
        cn = av * cn + (1.f - av) * c_reg[r];
        hv = av * hv + (1.f - av) * hold;
        c_reg[r] = cn;
        hn[arow * 136 + ni * 16 + l16] = f2bf(hv);
      }
    }
    __syncthreads();

    // ---- P7: state += h @ lin_w^T + lin_b; emit ----
    if (tid < 32) {
      int a = tid >> 1, oi = tid & 1;
      const float* lw = lnw + oi * 128;
      const unsigned short* hp = s_h + nxt * 2176 + a * 136;
      float accd = 0.f;
#pragma unroll
      for (int k = 0; k < 128; ++k) accd = fmaf(bf2f(hp[k]), lw[k], accd);
      float ns = s_state[a * 2 + oi] + accd + lnb[oi];
      s_state[a * 2 + oi] = ns;
      out[((size_t)(b * 64 + a0 + a) * T + t) * 2 + oi] = ns;
    }
    __syncthreads();
  }
}

// ---------------------------------------------------------------- launch ----
extern "C" void kernel_launch(void* const* d_in, const int* in_sizes, int n_in,
                              void* d_out, int out_size, void* d_ws, size_t ws_size,
                              hipStream_t stream) {
  (void)in_sizes; (void)n_in; (void)out_size; (void)ws_size;
  const float* cf = (const float*)d_in[0];
  const int* cav = (const int*)d_in[1];
  const float* hid = (const float*)d_in[2];
  const float* ctx = (const float*)d_in[3];
  const float* emb = (const float*)d_in[4];
  const int* mav = (const int*)d_in[5];
  const int* ntp = (const int*)d_in[6];
  const float* w1 = (const float*)d_in[7];
  const float* b1 = (const float*)d_in[8];
  const float* w2 = (const float*)d_in[9];
  const float* b2 = (const float*)d_in[10];
  const float* w3 = (const float*)d_in[11];
  const float* b3 = (const float*)d_in[12];
  const float* wq = (const float*)d_in[13];
  const float* bq = (const float*)d_in[14];
  const float* wk = (const float*)d_in[15];
  const float* bk = (const float*)d_in[16];
  const float* wv = (const float*)d_in[17];
  const float* bv = (const float*)d_in[18];
  const float* wo = (const float*)d_in[19];
  const float* bo = (const float*)d_in[20];
  const float* wih = (const float*)d_in[21];  // w_ih
  const float* whh = (const float*)d_in[22];  // w_hh
  const float* bih = (const float*)d_in[23];  // b_ih
  const float* bhh = (const float*)d_in[24];  // b_hh
  const float* lnw = (const float*)d_in[25];
  const float* lnb = (const float*)d_in[26];

  char* ws = (char*)d_ws;
  unsigned short* Kbf = (unsigned short*)(ws + 0);
  unsigned short* Vtbf = (unsigned short*)(ws + 16777216);
  unsigned short* WQs = (unsigned short*)(ws + 33554432);
  unsigned short* WOs = (unsigned short*)(ws + 33587200);
  unsigned short* W2s = (unsigned short*)(ws + 33619968);
  unsigned short* W3s = (unsigned short*)(ws + 33636352);
  unsigned short* WIHs = (unsigned short*)(ws + 33652736);
  unsigned short* WHHs = (unsigned short*)(ws + 33783808);
  float* B4s = (float*)(ws + 33914880);
  float* BQSs = (float*)(ws + 33916928);

  (void)hipFuncSetAttribute((const void*)kv_kernel,
                            hipFuncAttributeMaxDynamicSharedMemorySize, 99072);
  (void)hipFuncSetAttribute((const void*)decoder_kernel,
                            hipFuncAttributeMaxDynamicSharedMemorySize, 76160);

  convert_kernel<<<707, 256, 0, stream>>>(wq, wo, w2, w3, wih, whh, bih, bhh, bq,
                                          WQs, WOs, W2s, W3s, WIHs, WHHs, B4s, BQSs);
  kv_kernel<<<1024, 256, 99072, stream>>>(emb, wk, bk, wv, bv, Kbf, Vtbf);
  decoder_kernel<<<512, 512, 76160, stream>>>(
      cf, cav, hid, ctx, mav, ntp, w1, b1, b2, b3, bo, Kbf, Vtbf, WQs, WOs, W2s, W3s,
      WIHs, WHHs, B4s, BQSs, lnw, lnb, (float*)d_out);
}

// Round 8
// 2619.106 us; speedup vs baseline: 1.7284x; 1.6356x over previous
//
#include <hip/hip_runtime.h>
#include <cstdint>
#include <cstddef>

// Decoder_55654186222328 — MI355X, R8: persistent fp8 K/V in LDS.
// R7 post-mortem: kernel was purely K/V-streaming bound (11.2 GB HBM/L3 traffic
// = whole runtime). Fix: K/V are step-invariant -> convert to fp8 (e4m3) and
// keep them resident in LDS for all 80 steps. 256 blocks (128 b x 2 agent
// halves of 32) x 512 threads, 1 block/CU, LDS 162560 B.
// Attention: fp8 MFMA 16x16x32 (scores K=16 via quads 0-1; PV K=32/chunk);
// softmax exp2-domain, no max (scores O(0.1)); denominator via ones-fp8-MFMA
// on the same quantized P (quantization cancels in O/L). XOR-swizzled LDS for
// K/V (no padding); P overlays bufA during the chunk loop (wave-private).

typedef short short8 __attribute__((ext_vector_type(8)));
typedef float f32x4 __attribute__((ext_vector_type(4)));

#define LOG2E 1.4426950408889634f
#define QSCALE 0.36067376022224085f /* log2(e)/4 */

__device__ __forceinline__ unsigned short f2bf(float f) {
  union { float f; unsigned int u; } v; v.f = f;
  unsigned int u = v.u;
  return (unsigned short)((u + 0x7fffu + ((u >> 16) & 1u)) >> 16);  // RNE
}
__device__ __forceinline__ float sigm(float x) {
  return 1.f / (1.f + exp2f(-LOG2E * x));
}
__device__ __forceinline__ float tanh_f(float x) {
  return 1.f - 2.f / (1.f + exp2f(2.f * LOG2E * x));
}
__device__ __forceinline__ f32x4 splat4(float v) { f32x4 r = {v, v, v, v}; return r; }
__device__ __forceinline__ unsigned char f2fp8(float x) {
  return (unsigned char)__builtin_amdgcn_cvt_pk_fp8_f32(x, x, 0, false);
}
__device__ __forceinline__ f32x4 mfma_fp8(long a, long b, f32x4 c) {
  return __builtin_amdgcn_mfma_f32_16x16x32_fp8_fp8(a, b, c, 0, 0, 0);
}

// ---------------------------------------------------------------- convert ----
__global__ __launch_bounds__(256) void convert_kernel(
    const float* __restrict__ wq, const float* __restrict__ wo,
    const float* __restrict__ w2, const float* __restrict__ w3,
    const float* __restrict__ wih, const float* __restrict__ whh,
    const float* __restrict__ bih, const float* __restrict__ bhh,
    const float* __restrict__ bq,
    unsigned short* __restrict__ WQ, unsigned short* __restrict__ WO,
    unsigned short* __restrict__ W2, unsigned short* __restrict__ W3,
    unsigned short* __restrict__ WIH, unsigned short* __restrict__ WHH,
    float* __restrict__ B4, float* __restrict__ BQS) {
  int i = blockIdx.x * 256 + threadIdx.x;
  if (i >= 180864) return;
  if (i < 16384)       WQ[i] = f2bf(wq[i] * QSCALE);
  else if (i < 32768)  WO[i - 16384] = f2bf(wo[i - 16384]);
  else if (i < 40960)  W2[i - 32768] = f2bf(w2[i - 32768]);
  else if (i < 49152)  W3[i - 40960] = f2bf(w3[i - 40960]);
  else if (i < 114688) WIH[i - 49152] = f2bf(wih[i - 49152]);
  else if (i < 180224) WHH[i - 114688] = f2bf(whh[i - 114688]);
  else if (i < 180736) { int j = i - 180224; B4[j] = bih[j] + bhh[j]; }
  else                 { int j = i - 180736; BQS[j] = bq[j] * QSCALE; }
}

// ---------------------------------------------------------------- K/V --------
// K8[b][m][128] fp8; V8[b][d][512] fp8 (transposed). grid 1024 = 128 b x 8 chunks.
__global__ __launch_bounds__(256) void kv_kernel(
    const float* __restrict__ emb, const float* __restrict__ wk,
    const float* __restrict__ bk, const float* __restrict__ wv,
    const float* __restrict__ bv,
    unsigned char* __restrict__ K8, unsigned char* __restrict__ V8) {
  extern __shared__ char smem[];
  float* s_e = (float*)smem;            // [64][129]
  float* s_w = (float*)(smem + 33024);  // [128][129]
  const int tid = threadIdx.x;
  const int b = blockIdx.x >> 3;
  const int m0 = (blockIdx.x & 7) * 64;

  for (int i = tid; i < 8192; i += 256) {
    int row = i >> 7, col = i & 127;
    s_e[row * 129 + col] = emb[(size_t)(b * 512 + m0 + row) * 128 + col];
  }
  for (int i = tid; i < 16384; i += 256) {
    int row = i >> 7, col = i & 127;
    s_w[row * 129 + col] = wk[i];
  }
  __syncthreads();
  {  // K rows -> fp8
    const int dg = tid & 31, rg = tid >> 5;
    float acc[8][4];
#pragma unroll
    for (int rr = 0; rr < 8; ++rr)
#pragma unroll
      for (int j = 0; j < 4; ++j) acc[rr][j] = 0.f;
    for (int k = 0; k < 128; ++k) {
      float e[8];
#pragma unroll
      for (int rr = 0; rr < 8; ++rr) e[rr] = s_e[(rg * 8 + rr) * 129 + k];
#pragma unroll
      for (int j = 0; j < 4; ++j) {
        float w = s_w[(dg * 4 + j) * 129 + k];
#pragma unroll
        for (int rr = 0; rr < 8; ++rr) acc[rr][j] = fmaf(e[rr], w, acc[rr][j]);
      }
    }
#pragma unroll
    for (int rr = 0; rr < 8; ++rr)
#pragma unroll
      for (int j = 0; j < 4; ++j) {
        int d = dg * 4 + j;
        K8[(size_t)(b * 512 + m0 + rg * 8 + rr) * 128 + d] = f2fp8(acc[rr][j] + bk[d]);
      }
  }
  __syncthreads();
  for (int i = tid; i < 16384; i += 256) {
    int row = i >> 7, col = i & 127;
    s_w[row * 129 + col] = wv[i];
  }
  __syncthreads();
  {  // V transposed -> fp8
    const int r = tid & 63, dg = tid >> 6;
    float acc[32];
#pragma unroll
    for (int j = 0; j < 32; ++j) acc[j] = 0.f;
    for (int k = 0; k < 128; ++k) {
      float e = s_e[r * 129 + k];
#pragma unroll
      for (int j = 0; j < 32; ++j) acc[j] = fmaf(e, s_w[(dg * 32 + j) * 129 + k], acc[j]);
    }
#pragma unroll
    for (int j = 0; j < 32; ++j) {
      int d = dg * 32 + j;
      V8[(size_t)(b * 128 + d) * 512 + m0 + r] = f2fp8(acc[j] + bv[d]);
    }
  }
}

// ---------------------------------------------------------------- decoder ----
// grid 256 = 128 b x 2 agent-halves (32 agents). 512 threads = 8 waves.
// LDS (162560 B, 1 block/CU):
//   sK    @0      fp8 [512][128] XOR-swz  65536   (persistent)
//   sV    @65536  fp8 [128][512] XOR-swz  65536   (persistent, transposed)
//   bufA  @131072 u16 [32][136]            8704   (h1 | P-overlay 8x[32][32]fp8 | x)
//   bufB  @139776 u16 [32][136]            8704   (e | o)
//   s_h   @148480 u16 [32][136]            8704   (single buffer + intra-P6 barrier)
//   zone  @157184 4608: h2 u16 [32][72] then qf8 u8 [32][136] (lifetimes disjoint)
//   state @161792 f32 [64]                  256
//   maskb @162048 u8 [512]                  512
__global__ __launch_bounds__(512, 2) void decoder_kernel(
    const float* __restrict__ cf, const int* __restrict__ cav,
    const float* __restrict__ hid,
    const float* __restrict__ ctx, const int* __restrict__ mav,
    const int* __restrict__ ntp,
    const float* __restrict__ w1, const float* __restrict__ b1,
    const float* __restrict__ b2, const float* __restrict__ b3,
    const float* __restrict__ boP,
    const unsigned char* __restrict__ K8, const unsigned char* __restrict__ V8,
    const unsigned short* __restrict__ WQ, const unsigned short* __restrict__ WO,
    const unsigned short* __restrict__ W2, const unsigned short* __restrict__ W3,
    const unsigned short* __restrict__ WIH, const unsigned short* __restrict__ WHH,
    const float* __restrict__ B4, const float* __restrict__ BQS,
    const float* __restrict__ lnw, const float* __restrict__ lnb,
    float* __restrict__ out) {
  extern __shared__ char smem[];
  unsigned short* s_bufA = (unsigned short*)(smem + 131072);
  unsigned short* s_bufB = (unsigned short*)(smem + 139776);
  unsigned short* s_h = (unsigned short*)(smem + 148480);
  unsigned short* s_h2 = (unsigned short*)(smem + 157184);
  unsigned char* s_qf8 = (unsigned char*)(smem + 157184);
  float* s_state = (float*)(smem + 161792);
  unsigned char* s_maskb = (unsigned char*)(smem + 162048);

  const int tid = threadIdx.x;
  const int wave = tid >> 6;
  const int lane = tid & 63;
  const int quad = lane >> 4;
  const int l16 = lane & 15;

  const int b = blockIdx.x & 127;
  const int a0 = (blockIdx.x >> 7) * 32;
  const int T = *ntp;
  const f32x4 zero4 = {0.f, 0.f, 0.f, 0.f};
  const long kOnes = 0x3838383838383838L;  // fp8 e4m3 1.0 x8

  // ---- preload persistent K/V into LDS with XOR swizzle ----
  {
    const unsigned long long* Kg = (const unsigned long long*)(K8 + (size_t)b * 65536);
    for (int i = tid; i < 8192; i += 512) {
      int tok = i >> 4, seg = i & 15;
      *(unsigned long long*)(smem + tok * 128 + ((seg * 8) ^ ((tok & 15) * 8))) =
          Kg[(size_t)tok * 16 + seg];
    }
    const unsigned long long* Vg = (const unsigned long long*)(V8 + (size_t)b * 65536);
    for (int i = tid; i < 8192; i += 512) {
      int d = i >> 6, seg = i & 63;
      *(unsigned long long*)(smem + 65536 + d * 512 + ((seg * 8) ^ ((d & 15) * 8))) =
          Vg[(size_t)d * 64 + seg];
    }
  }
  // ---- init ----
  if (tid < 64) {
    int a = tid >> 1, oi = tid & 1;
    s_state[a * 2 + oi] = cf[(size_t)(b * 64 + a0 + a) * 2 + oi];
  }
  s_maskb[tid] = mav[b * 512 + tid] ? 1 : 0;
  {  // h0 (32 agents x 128 -> 8 per thread)
    int idx = tid * 8;
    int a = idx >> 7, n0 = idx & 127;
    const float* hp = hid + (size_t)(b * 64 + a0 + a) * 128 + n0;
    short8 v;
#pragma unroll
    for (int j = 0; j < 8; ++j) v[j] = (short)f2bf(hp[j]);
    *(short8*)(s_h + a * 136 + n0) = v;
  }
  float c_reg[2][4], avl[2][4];
#pragma unroll
  for (int mt = 0; mt < 2; ++mt)
#pragma unroll
    for (int r = 0; r < 4; ++r) {
      int a = mt * 16 + quad * 4 + r;
      c_reg[mt][r] = ctx[(size_t)(b * 64 + a0 + a) * 128 + wave * 16 + l16];
      avl[mt][r] = (cav[b * 64 + a0 + a] != 0) ? 1.f : 0.f;
    }
  __syncthreads();

#pragma unroll 1
  for (int t = 0; t < T; ++t) {
    // ---- P0: h1 = relu(state @ w1^T + b1) -> bufA ----
    {
      int a = tid >> 4, n0 = (tid & 15) * 8;
      float st0 = s_state[a * 2], st1 = s_state[a * 2 + 1];
      const float* wp = w1 + n0 * 2;
      const float* bp = b1 + n0;
      short8 v;
#pragma unroll
      for (int j = 0; j < 8; ++j) {
        float x = fmaf(wp[j * 2], st0, fmaf(wp[j * 2 + 1], st1, bp[j]));
        v[j] = (short)f2bf(fmaxf(x, 0.f));
      }
      *(short8*)(s_bufA + a * 136 + n0) = v;
    }
    __syncthreads();

    // ---- P1: h2 = relu(h1 @ w2^T + b2)  M32 N64 K128 -> zone ----
    {
      int mt = wave >> 2, nt = wave & 3;
      f32x4 acc = splat4(b2[nt * 16 + l16]);
#pragma unroll
      for (int kt = 0; kt < 4; ++kt) {
        short8 a8 = *(const short8*)(s_bufA + (mt * 16 + l16) * 136 + kt * 32 + quad * 8);
        short8 b8 = *(const short8*)(W2 + ((nt * 16 + l16) * 128 + kt * 32 + quad * 8));
        acc = __builtin_amdgcn_mfma_f32_16x16x32_bf16(a8, b8, acc, 0, 0, 0);
      }
#pragma unroll
      for (int r = 0; r < 4; ++r)
        s_h2[(mt * 16 + quad * 4 + r) * 72 + nt * 16 + l16] = f2bf(fmaxf(acc[r], 0.f));
    }
    __syncthreads();

    // ---- P2: e = h2 @ w3^T + b3  M32 N128 K64 -> bufB ----
    {
      int nt = wave;
      float bv = b3[nt * 16 + l16];
      short8 b8[2];
#pragma unroll
      for (int kt = 0; kt < 2; ++kt)
        b8[kt] = *(const short8*)(W3 + ((nt * 16 + l16) * 64 + kt * 32 + quad * 8));
#pragma unroll
      for (int mt = 0; mt < 2; ++mt) {
        f32x4 acc = splat4(bv);
#pragma unroll
        for (int kt = 0; kt < 2; ++kt) {
          short8 a8 = *(const short8*)(s_h2 + (mt * 16 + l16) * 72 + kt * 32 + quad * 8);
          acc = __builtin_amdgcn_mfma_f32_16x16x32_bf16(a8, b8[kt], acc, 0, 0, 0);
        }
#pragma unroll
        for (int r = 0; r < 4; ++r)
          s_bufB[(mt * 16 + quad * 4 + r) * 136 + nt * 16 + l16] = f2bf(acc[r]);
      }
    }
    __syncthreads();

    // ---- P3: q = e @ wq_s^T + bq_s -> fp8 qf8 (overlays h2; h2 dead) ----
    {
      int nt = wave;
      float bv = BQS[nt * 16 + l16];
      short8 b8[4];
#pragma unroll
      for (int kt = 0; kt < 4; ++kt)
        b8[kt] = *(const short8*)(WQ + ((nt * 16 + l16) * 128 + kt * 32 + quad * 8));
#pragma unroll
      for (int mt = 0; mt < 2; ++mt) {
        f32x4 acc = splat4(bv);
#pragma unroll
        for (int kt = 0; kt < 4; ++kt) {
          short8 a8 = *(const short8*)(s_bufB + (mt * 16 + l16) * 136 + kt * 32 + quad * 8);
          acc = __builtin_amdgcn_mfma_f32_16x16x32_bf16(a8, b8[kt], acc, 0, 0, 0);
        }
#pragma unroll
        for (int r = 0; r < 4; ++r)
          s_qf8[(mt * 16 + quad * 4 + r) * 136 + nt * 16 + l16] = f2fp8(acc[r]);
      }
    }
    __syncthreads();

    // ---- P4: attention (all-LDS fp8). wave = head. ----
    {
      const int h = wave;
      const char* sKb = (const char*)smem;
      const char* sVrow = (const char*)(smem + 65536) + (h * 16 + l16) * 512;
      char* sPw = (char*)s_bufA + wave * 1024;  // P [32][32] fp8, wave-private
      long qA[2];
#pragma unroll
      for (int mt = 0; mt < 2; ++mt)
        qA[mt] = (quad < 2)
                     ? *(const long*)(s_qf8 + (mt * 16 + l16) * 136 + h * 16 + quad * 8)
                     : 0L;
      const int koff = (h * 16 + quad * 8) ^ (l16 * 8);
      f32x4 O[2], L4[2];
      O[0] = zero4; O[1] = zero4; L4[0] = zero4; L4[1] = zero4;
#pragma unroll 1
      for (int c = 0; c < 16; ++c) {
        f32x4 S[2][2];
#pragma unroll
        for (int nt = 0; nt < 2; ++nt) {
          long kB = 0L;
          if (quad < 2)
            kB = *(const long*)(sKb + (c * 32 + nt * 16 + l16) * 128 + koff);
          S[0][nt] = mfma_fp8(qA[0], kB, zero4);
          S[1][nt] = mfma_fp8(qA[1], kB, zero4);
        }
#pragma unroll
        for (int nt = 0; nt < 2; ++nt) {
          const int col = nt * 16 + l16;
          const bool mv = s_maskb[c * 32 + col] != 0;
#pragma unroll
          for (int mt = 0; mt < 2; ++mt)
#pragma unroll
            for (int r = 0; r < 4; ++r) {
              float p = mv ? exp2f(S[mt][nt][r]) : 0.f;
              sPw[(mt * 16 + quad * 4 + r) * 32 + col] = (char)f2fp8(p);
            }
        }
        __asm__ volatile("s_waitcnt lgkmcnt(0)" ::: "memory");  // P writes -> reads (same wave)
        long b8 = *(const long*)(sVrow + ((c * 32 + quad * 8) ^ (l16 * 8)));
#pragma unroll
        for (int mt = 0; mt < 2; ++mt) {
          long a8 = *(const long*)(sPw + (mt * 16 + l16) * 32 + quad * 8);
          O[mt] = mfma_fp8(a8, b8, O[mt]);
          L4[mt] = mfma_fp8(a8, kOnes, L4[mt]);
        }
      }
      // o -> bufB (e dead)
#pragma unroll
      for (int mt = 0; mt < 2; ++mt)
#pragma unroll
        for (int r = 0; r < 4; ++r)
          s_bufB[(mt * 16 + quad * 4 + r) * 136 + h * 16 + l16] =
              f2bf(O[mt][r] / L4[mt][r]);
    }
    __syncthreads();

    // ---- P5: x = o @ wo^T + bo -> bufA (P region dead) ----
    {
      int nt = wave;
      float bv = boP[nt * 16 + l16];
      short8 b8[4];
#pragma unroll
      for (int kt = 0; kt < 4; ++kt)
        b8[kt] = *(const short8*)(WO + ((nt * 16 + l16) * 128 + kt * 32 + quad * 8));
#pragma unroll
      for (int mt = 0; mt < 2; ++mt) {
        f32x4 acc = splat4(bv);
#pragma unroll
        for (int kt = 0; kt < 4; ++kt) {
          short8 a8 = *(const short8*)(s_bufB + (mt * 16 + l16) * 136 + kt * 32 + quad * 8);
          acc = __builtin_amdgcn_mfma_f32_16x16x32_bf16(a8, b8[kt], acc, 0, 0, 0);
        }
#pragma unroll
        for (int r = 0; r < 4; ++r)
          s_bufA[(mt * 16 + quad * 4 + r) * 136 + nt * 16 + l16] = f2bf(acc[r]);
      }
    }
    __syncthreads();

    // ---- P6: LSTM gates + elementwise ----
    {
      const int ni = wave;
      const int wrow = ni * 16 + l16;
      f32x4 gi[2], gf[2], gg[2], go[2];
#pragma unroll
      for (int mt = 0; mt < 2; ++mt) {
        gi[mt] = splat4(B4[wrow]);
        gf[mt] = splat4(B4[128 + wrow]);
        gg[mt] = splat4(B4[256 + wrow]);
        go[mt] = splat4(B4[384 + wrow]);
      }
#pragma unroll
      for (int kt = 0; kt < 4; ++kt) {
        short8 b_i = *(const short8*)(WIH + ((0 + wrow) * 128 + kt * 32 + quad * 8));
        short8 b_f = *(const short8*)(WIH + ((128 + wrow) * 128 + kt * 32 + quad * 8));
        short8 b_g = *(const short8*)(WIH + ((256 + wrow) * 128 + kt * 32 + quad * 8));
        short8 b_o = *(const short8*)(WIH + ((384 + wrow) * 128 + kt * 32 + quad * 8));
#pragma unroll
        for (int mt = 0; mt < 2; ++mt) {
          short8 a8 = *(const short8*)(s_bufA + (mt * 16 + l16) * 136 + kt * 32 + quad * 8);
          gi[mt] = __builtin_amdgcn_mfma_f32_16x16x32_bf16(a8, b_i, gi[mt], 0, 0, 0);
          gf[mt] = __builtin_amdgcn_mfma_f32_16x16x32_bf16(a8, b_f, gf[mt], 0, 0, 0);
          gg[mt] = __builtin_amdgcn_mfma_f32_16x16x32_bf16(a8, b_g, gg[mt], 0, 0, 0);
          go[mt] = __builtin_amdgcn_mfma_f32_16x16x32_bf16(a8, b_o, go[mt], 0, 0, 0);
        }
      }
#pragma unroll
      for (int kt = 0; kt < 4; ++kt) {
        short8 b_i = *(const short8*)(WHH + ((0 + wrow) * 128 + kt * 32 + quad * 8));
        short8 b_f = *(const short8*)(WHH + ((128 + wrow) * 128 + kt * 32 + quad * 8));
        short8 b_g = *(const short8*)(WHH + ((256 + wrow) * 128 + kt * 32 + quad * 8));
        short8 b_o = *(const short8*)(WHH + ((384 + wrow) * 128 + kt * 32 + quad * 8));
#pragma unroll
        for (int mt = 0; mt < 2; ++mt) {
          short8 a8 = *(const short8*)(s_h + (mt * 16 + l16) * 136 + kt * 32 + quad * 8);
          gi[mt] = __builtin_amdgcn_mfma_f32_16x16x32_bf16(a8, b_i, gi[mt], 0, 0, 0);
          gf[mt] = __builtin_amdgcn_mfma_f32_16x16x32_bf16(a8, b_f, gf[mt], 0, 0, 0);
          gg[mt] = __builtin_amdgcn_mfma_f32_16x16x32_bf16(a8, b_g, gg[mt], 0, 0, 0);
          go[mt] = __builtin_amdgcn_mfma_f32_16x16x32_bf16(a8, b_o, go[mt], 0, 0, 0);
        }
      }
      float hnew[2][4];
#pragma unroll
      for (int mt = 0; mt < 2; ++mt)
#pragma unroll
        for (int r = 0; r < 4; ++r) {
          float iv = sigm(gi[mt][r]);
          float fv = sigm(gf[mt][r]);
          float gv = tanh_f(gg[mt][r]);
          float ov = sigm(go[mt][r]);
          float cn = fmaf(fv, c_reg[mt][r], iv * gv);
          float hv = ov * tanh_f(cn);
          int arow = mt * 16 + quad * 4 + r;
          float av = avl[mt][r];
          union { unsigned int u; float f; } ho;
          ho.u = ((unsigned int)s_h[arow * 136 + ni * 16 + l16]) << 16;
          c_reg[mt][r] = av * cn + (1.f - av) * c_reg[mt][r];
          hnew[mt][r] = av * hv + (1.f - av) * ho.f;
        }
      __syncthreads();  // all h reads (incl. MFMA A-frags) done before overwrite
#pragma unroll
      for (int mt = 0; mt < 2; ++mt)
#pragma unroll
        for (int r = 0; r < 4; ++r) {
          int arow = mt * 16 + quad * 4 + r;
          s_h[arow * 136 + ni * 16 + l16] = f2bf(hnew[mt][r]);
        }
    }
    __syncthreads();

    // ---- P7: state += h @ lin_w^T + lin_b; emit ----
    if (tid < 64) {
      int a = tid >> 1, oi = tid & 1;
      const float* lw = lnw + oi * 128;
      const unsigned short* hp = s_h + a * 136;
      float accd = 0.f;
#pragma unroll
      for (int k = 0; k < 128; ++k) {
        union { unsigned int u; float f; } hv;
        hv.u = ((unsigned int)hp[k]) << 16;
        accd = fmaf(hv.f, lw[k], accd);
      }
      float ns = s_state[a * 2 + oi] + accd + lnb[oi];
      s_state[a * 2 + oi] = ns;
      out[((size_t)(b * 64 + a0 + a) * T + t) * 2 + oi] = ns;
    }
    __syncthreads();
  }
}

// ---------------------------------------------------------------- launch ----
extern "C" void kernel_launch(void* const* d_in, const int* in_sizes, int n_in,
                              void* d_out, int out_size, void* d_ws, size_t ws_size,
                              hipStream_t stream) {
  (void)in_sizes; (void)n_in; (void)out_size; (void)ws_size;
  const float* cf = (const float*)d_in[0];
  const int* cav = (const int*)d_in[1];
  const float* hid = (const float*)d_in[2];
  const float* ctx = (const float*)d_in[3];
  const float* emb = (const float*)d_in[4];
  const int* mav = (const int*)d_in[5];
  const int* ntp = (const int*)d_in[6];
  const float* w1 = (const float*)d_in[7];
  const float* b1 = (const float*)d_in[8];
  const float* w2 = (const float*)d_in[9];
  const float* b2 = (const float*)d_in[10];
  const float* w3 = (const float*)d_in[11];
  const float* b3 = (const float*)d_in[12];
  const float* wq = (const float*)d_in[13];
  const float* bq = (const float*)d_in[14];
  const float* wk = (const float*)d_in[15];
  const float* bk = (const float*)d_in[16];
  const float* wv = (const float*)d_in[17];
  const float* bv = (const float*)d_in[18];
  const float* wo = (const float*)d_in[19];
  const float* bo = (const float*)d_in[20];
  const float* wih = (const float*)d_in[21];  // w_ih
  const float* whh = (const float*)d_in[22];  // w_hh
  const float* bih = (const float*)d_in[23];  // b_ih
  const float* bhh = (const float*)d_in[24];  // b_hh
  const float* lnw = (const float*)d_in[25];
  const float* lnb = (const float*)d_in[26];

  char* ws = (char*)d_ws;
  unsigned char* K8 = (unsigned char*)(ws + 0);         // 8,388,608
  unsigned char* V8 = (unsigned char*)(ws + 8388608);   // 8,388,608
  unsigned short* WQs = (unsigned short*)(ws + 16777216);
  unsigned short* WOs = (unsigned short*)(ws + 16809984);
  unsigned short* W2s = (unsigned short*)(ws + 16842752);
  unsigned short* W3s = (unsigned short*)(ws + 16859136);
  unsigned short* WIHs = (unsigned short*)(ws + 16875520);
  unsigned short* WHHs = (unsigned short*)(ws + 17006592);
  float* B4s = (float*)(ws + 17137664);
  float* BQSs = (float*)(ws + 17139712);

  (void)hipFuncSetAttribute((const void*)kv_kernel,
                            hipFuncAttributeMaxDynamicSharedMemorySize, 99072);
  (void)hipFuncSetAttribute((const void*)decoder_kernel,
                            hipFuncAttributeMaxDynamicSharedMemorySize, 162560);

  convert_kernel<<<707, 256, 0, stream>>>(wq, wo, w2, w3, wih, whh, bih, bhh, bq,
                                          WQs, WOs, W2s, W3s, WIHs, WHHs, B4s, BQSs);
  kv_kernel<<<1024, 256, 99072, stream>>>(emb, wk, bk, wv, bv, K8, V8);
  decoder_kernel<<<256, 512, 162560, stream>>>(
      cf, cav, hid, ctx, mav, ntp, w1, b1, b2, b3, bo, K8, V8, WQs, WOs, W2s, W3s,
      WIHs, WHHs, B4s, BQSs, lnw, lnb, (float*)d_out);
}